// Round 1
// baseline (283.254 us; speedup 1.0000x reference)
//
#include <hip/hip_runtime.h>

// Haar decompose->reconstruct with channel-sum collapses algebraically to:
//   out[b,0,h,w] = 0.5f * (x[b,0,h,w] + x[b,1,h,w] + x[b,2,h,w])
// Pure memory-bound elementwise kernel. Shapes fixed: B=16, C=3, H=W=1024.
//
// float4 per thread: 16 B/lane loads/stores (coalescing sweet spot).
// Plane = 1024*1024 floats = 262144 float4 (2^18) -> shift/mask for b,p.

#define P4 262144          // float4s per (b,c) plane
#define TOTAL4 (16 * P4)   // output float4 count = 4194304

__global__ __launch_bounds__(256) void haar_channel_sum_kernel(
    const float4* __restrict__ in, float4* __restrict__ out) {
    int gid = blockIdx.x * blockDim.x + threadIdx.x;
    // grid exactly covers TOTAL4, no bounds check needed (16384 blocks * 256)
    int b = gid >> 18;          // / P4
    int p = gid & (P4 - 1);     // % P4
    const float4* base = in + (size_t)(b * 3) * P4 + p;
    float4 a0 = base[0];
    float4 a1 = base[P4];
    float4 a2 = base[2 * P4];
    float4 r;
    r.x = 0.5f * (a0.x + a1.x + a2.x);
    r.y = 0.5f * (a0.y + a1.y + a2.y);
    r.z = 0.5f * (a0.z + a1.z + a2.z);
    r.w = 0.5f * (a0.w + a1.w + a2.w);
    out[gid] = r;
}

extern "C" void kernel_launch(void* const* d_in, const int* in_sizes, int n_in,
                              void* d_out, int out_size, void* d_ws, size_t ws_size,
                              hipStream_t stream) {
    const float4* x = (const float4*)d_in[0];
    float4* out = (float4*)d_out;
    const int threads = 256;
    const int blocks = TOTAL4 / threads;   // 16384
    haar_channel_sum_kernel<<<blocks, threads, 0, stream>>>(x, out);
}

// Round 3
// 274.293 us; speedup vs baseline: 1.0327x; 1.0327x over previous
//
#include <hip/hip_runtime.h>

// Haar decompose->reconstruct with channel-sum collapses algebraically to:
//   out[b,0,h,w] = 0.5f * (x[b,0,h,w] + x[b,1,h,w] + x[b,2,h,w])
// Pure memory-bound elementwise kernel. Shapes fixed: B=16, C=3, H=W=1024.
//
// Round 3: same as round 2 but with a native clang vector type — HIP's
// float4 is a struct (HIP_vector_type) and __builtin_nontemporal_* rejects
// it; ext_vector_type(4) float is accepted and layout-identical (16 B).
// nt loads/stores keep the 256 MiB single-touch stream out of L2/L3;
// 2 vec4/thread gives 6 outstanding HBM loads for latency hiding, each
// instruction fully wave-coalesced (block spans 512 consecutive vec4s).

typedef float v4f __attribute__((ext_vector_type(4)));

#define P4 262144           // vec4s per (b,c) plane (1024*1024/4 = 2^18)
#define TOTAL4 (16 * P4)    // output vec4 count = 4194304

__global__ __launch_bounds__(256) void haar_channel_sum_kernel(
    const v4f* __restrict__ in, v4f* __restrict__ out) {
    int gid0 = blockIdx.x * 512 + threadIdx.x;   // first vec4 of this thread
    int gid1 = gid0 + 256;                       // second (same block's span)

    int b0 = gid0 >> 18;          // / P4
    int p0 = gid0 & (P4 - 1);     // % P4
    int b1 = gid1 >> 18;
    int p1 = gid1 & (P4 - 1);

    const v4f* base0 = in + (size_t)(b0 * 3) * P4 + p0;
    const v4f* base1 = in + (size_t)(b1 * 3) * P4 + p1;

    v4f a0 = __builtin_nontemporal_load(base0);
    v4f a1 = __builtin_nontemporal_load(base0 + P4);
    v4f a2 = __builtin_nontemporal_load(base0 + 2 * P4);
    v4f c0 = __builtin_nontemporal_load(base1);
    v4f c1 = __builtin_nontemporal_load(base1 + P4);
    v4f c2 = __builtin_nontemporal_load(base1 + 2 * P4);

    v4f r0 = 0.5f * (a0 + a1 + a2);
    v4f r1 = 0.5f * (c0 + c1 + c2);

    __builtin_nontemporal_store(r0, out + gid0);
    __builtin_nontemporal_store(r1, out + gid1);
}

extern "C" void kernel_launch(void* const* d_in, const int* in_sizes, int n_in,
                              void* d_out, int out_size, void* d_ws, size_t ws_size,
                              hipStream_t stream) {
    const v4f* x = (const v4f*)d_in[0];
    v4f* out = (v4f*)d_out;
    const int threads = 256;
    const int blocks = TOTAL4 / (threads * 2);   // 8192 blocks, 2 vec4/thread
    haar_channel_sum_kernel<<<blocks, threads, 0, stream>>>(x, out);
}

// Round 4
// 271.888 us; speedup vs baseline: 1.0418x; 1.0088x over previous
//
#include <hip/hip_runtime.h>

// Haar decompose->reconstruct with channel-sum collapses algebraically to:
//   out[b,0,h,w] = 0.5f * (x[b,0,h,w] + x[b,1,h,w] + x[b,2,h,w])
// Pure memory-bound elementwise kernel. Shapes fixed: B=16, C=3, H=W=1024.
//
// Round 4: 4 vec4/thread (12 outstanding nt loads per thread) for deeper
// latency hiding. Block spans 1024 consecutive vec4s; every load/store
// instruction remains fully wave-coalesced (lane i -> addr + i*16B).
// nt flags keep the 256 MiB single-touch stream out of L2/L3.

typedef float v4f __attribute__((ext_vector_type(4)));

#define P4 262144           // vec4s per (b,c) plane (1024*1024/4 = 2^18)
#define TOTAL4 (16 * P4)    // output vec4 count = 4194304
#define VPT 4               // vec4s per thread

__global__ __launch_bounds__(256) void haar_channel_sum_kernel(
    const v4f* __restrict__ in, v4f* __restrict__ out) {
    int gid[VPT];
    v4f a[VPT], b[VPT], c[VPT];

    int base_gid = blockIdx.x * (256 * VPT) + threadIdx.x;
#pragma unroll
    for (int k = 0; k < VPT; ++k) {
        gid[k] = base_gid + k * 256;
        int bb = gid[k] >> 18;           // / P4
        int pp = gid[k] & (P4 - 1);      // % P4
        const v4f* base = in + (size_t)(bb * 3) * P4 + pp;
        a[k] = __builtin_nontemporal_load(base);
        b[k] = __builtin_nontemporal_load(base + P4);
        c[k] = __builtin_nontemporal_load(base + 2 * P4);
    }
#pragma unroll
    for (int k = 0; k < VPT; ++k) {
        v4f r = 0.5f * (a[k] + b[k] + c[k]);
        __builtin_nontemporal_store(r, out + gid[k]);
    }
}

extern "C" void kernel_launch(void* const* d_in, const int* in_sizes, int n_in,
                              void* d_out, int out_size, void* d_ws, size_t ws_size,
                              hipStream_t stream) {
    const v4f* x = (const v4f*)d_in[0];
    v4f* out = (v4f*)d_out;
    const int threads = 256;
    const int blocks = TOTAL4 / (threads * VPT);   // 4096 blocks
    haar_channel_sum_kernel<<<blocks, threads, 0, stream>>>(x, out);
}